// Round 1
// baseline (542.206 us; speedup 1.0000x reference)
//
#include <hip/hip_runtime.h>
#include <cstdint>
#include <cstddef>

// Problem constants: x(32,64,512,27) f32, conv_w(384,64), conv_b(384), A(3,27,27),
// gamma/beta(128). out = relu(BN(einsum)) shape (32,128,512,27) f32.
#define NT_TOTAL 16384   // N*T = 32*512
#define R_NT 8           // (n,t) rows per block
#define NBLK 2048        // NT_TOTAL / R_NT
#define CNT_F 442368.0f  // N*T*V = 32*512*27 elements per channel

// K1 dynamic-LDS layout (bytes). All row strides padded for bank spread + 16B align.
#define XA_OFF 0           // xa: 256 rows x 400B (192 bf16 + pad). reused as z-tile later
#define XA_STRIDE 400
#define R2_OFF 102400      // phase A: xs 512 rows x 80B (32 bf16 + pad); phase B: wBT 128 rows x 400B
#define XS_STRIDE 80
#define WBT_STRIDE 400
#define CB_OFF 153600      // conv_b 384 f32
#define SA_OFF 155136      // sumA[k][w] 3x32 f32
#define ST_OFF 155520      // stats 256 f32 (sum, sumsq per channel)
#define LDS_BYTES 156544
#define ZL_STRIDE 260      // z-tile in LDS: 256 rows x (128 bf16 + pad)

typedef __attribute__((ext_vector_type(8))) short short8;  // 8 bf16 = 4 VGPR (MFMA A/B frag)
typedef __attribute__((ext_vector_type(4))) float f32x4;   // MFMA C/D frag

__device__ __forceinline__ unsigned short f2bf(float f) {
  unsigned int u = __float_as_uint(f);
  u = u + 0x7FFFu + ((u >> 16) & 1u);   // RNE
  return (unsigned short)(u >> 16);
}
__device__ __forceinline__ float bf2f(unsigned short b) {
  return __uint_as_float(((unsigned int)b) << 16);
}

// ---------------------------------------------------------------------------
// K1: per block, R_NT=8 (n,t) positions.
//  phase A (MFMA): xa[(r,w)][(k,ci)] = sum_v x[n,ci,t,v] * A[k,v,w]   (bf16 in LDS)
//  phase B (MFMA): z[(r,w)][c] = sum_{k,ci} xa * conv_w[k*128+c][ci]  (f32 acc)
//  epilogue: + bias2[c,w] = sum_k conv_b[k*128+c]*sumA[k][w]; stats; z->LDS; coalesced store
// ---------------------------------------------------------------------------
template <bool ZBF16>
__global__ __launch_bounds__(512, 2) void gcn_k1(
    const float* __restrict__ x, const float* __restrict__ cw,
    const float* __restrict__ cb, const float* __restrict__ A,
    float* __restrict__ zout_f32, unsigned short* __restrict__ zout_bf16,
    float* __restrict__ partial) {
  extern __shared__ char smem[];
  const int tid = threadIdx.x;
  const int lane = tid & 63;
  const int wid = tid >> 6;
  const int blk = blockIdx.x;
  const int nt0 = blk * R_NT;

  // ---- early global loads ----
  // x row for thread (ci = tid&63, r = wid): 27 contiguous f32
  const int ci = tid & 63;
  const int r = wid;
  const int ntI = nt0 + r;
  const int nI = ntI >> 9;
  const int tI = ntI & 511;
  const float* xr = x + ((size_t)(nI * 64 + ci) * 512 + tI) * 27;
  float xrow[27];
#pragma unroll
  for (int v = 0; v < 27; ++v) xrow[v] = xr[v];

  // conv_w gathered in wBT order: pair slot p -> (c = p/96, kp = p%96),
  // kp -> k = kp/32, ci-pair = kp%32; source pair q = (k*128+c)*32 + cip
  float2 wreg[24];
  {
    const float2* cw2 = (const float2*)cw;
#pragma unroll
    for (int i = 0; i < 24; ++i) {
      const int p = i * 512 + tid;
      const int c = p / 96;
      const int kp = p % 96;
      const int k = kp >> 5;
      const int cip = kp & 31;
      wreg[i] = cw2[(k * 128 + c) * 32 + cip];
    }
  }

  // A-operand frags for phase A, held in registers: Aop[k] is (w x v), rows w.
  // frag layout: row = lane&15 (+16*mt), k-dim elem j -> v = (lane>>4)*8 + j
  short8 aop[3][2];
#pragma unroll
  for (int k = 0; k < 3; ++k)
#pragma unroll
    for (int mt = 0; mt < 2; ++mt) {
      const int wr = mt * 16 + (lane & 15);
#pragma unroll
      for (int j = 0; j < 8; ++j) {
        const int v = (lane >> 4) * 8 + j;
        float val = (wr < 27 && v < 27) ? A[k * 729 + v * 27 + wr] : 0.f;
        aop[k][mt][j] = (short)f2bf(val);
      }
    }

  // ---- LDS staging ----
  if (tid < 256) ((float*)(smem + ST_OFF))[tid] = 0.f;
  if (tid < 384) ((float*)(smem + CB_OFF))[tid] = cb[tid];
  if (tid < 81) {
    const int k = tid / 27, w = tid % 27;
    float s = 0.f;
#pragma unroll
    for (int v = 0; v < 27; ++v) s += A[k * 729 + v * 27 + w];
    ((float*)(smem + SA_OFF))[k * 32 + w] = s;
  }
  // xs: row (r,ci), 27 bf16 + zero pad to 32 (pad MUST be zero: feeds MFMA K)
  {
    char* base = smem + R2_OFF + r * (64 * XS_STRIDE) + ci * XS_STRIDE;
#pragma unroll
    for (int i = 0; i < 16; ++i) {
      const int v0 = 2 * i, v1 = 2 * i + 1;
      unsigned int b0 = (v0 < 27) ? (unsigned int)f2bf(xrow[v0]) : 0u;
      unsigned int b1 = (v1 < 27) ? (unsigned int)f2bf(xrow[v1]) : 0u;
      *(unsigned int*)(base + i * 4) = b0 | (b1 << 16);
    }
  }
  __syncthreads();

  // ---- phase A: one wave per r ----
  {
    const int r2 = wid;
    short8 bfr[4];
#pragma unroll
    for (int nt2 = 0; nt2 < 4; ++nt2) {
      const int ci2 = nt2 * 16 + (lane & 15);
      bfr[nt2] = *(const short8*)(smem + R2_OFF + r2 * (64 * XS_STRIDE) +
                                  ci2 * XS_STRIDE + (lane >> 4) * 16);
    }
#pragma unroll
    for (int k = 0; k < 3; ++k)
#pragma unroll
      for (int mt = 0; mt < 2; ++mt)
#pragma unroll
        for (int nt2 = 0; nt2 < 4; ++nt2) {
          f32x4 d = {0.f, 0.f, 0.f, 0.f};
          d = __builtin_amdgcn_mfma_f32_16x16x32_bf16(aop[k][mt], bfr[nt2], d, 0, 0, 0);
          const int ciW = nt2 * 16 + (lane & 15);
#pragma unroll
          for (int reg = 0; reg < 4; ++reg) {
            const int w = mt * 16 + (lane >> 4) * 4 + reg;
            if (w < 27) {  // pad rows w>=27 never read meaningfully (rows independent)
              const int m = r2 * 32 + w;
              *(unsigned short*)(smem + XA_OFF + m * XA_STRIDE + (k * 64 + ciW) * 2) =
                  f2bf(d[reg]);
            }
          }
        }
  }
  __syncthreads();

  // ---- wBT store (overwrites xs region; xs dead) ----
#pragma unroll
  for (int i = 0; i < 24; ++i) {
    const int p = i * 512 + tid;
    const int c = p / 96;
    const int kp = p % 96;
    unsigned int b0 = f2bf(wreg[i].x);
    unsigned int b1 = f2bf(wreg[i].y);
    *(unsigned int*)(smem + R2_OFF + c * WBT_STRIDE + kp * 4) = b0 | (b1 << 16);
  }
  __syncthreads();

  // ---- phase B: M=256, N=128, K=192; 8 waves = 4 mgrp x 2 ngrp ----
  const int mgrp = wid >> 1;
  const int ngrp = wid & 1;
  f32x4 acc[4][4];
#pragma unroll
  for (int a = 0; a < 4; ++a)
#pragma unroll
    for (int b = 0; b < 4; ++b) acc[a][b] = (f32x4){0.f, 0.f, 0.f, 0.f};

#pragma unroll
  for (int ks = 0; ks < 6; ++ks) {
    short8 afr[4], bfr2[4];
#pragma unroll
    for (int mt = 0; mt < 4; ++mt) {
      const int m = mgrp * 64 + mt * 16 + (lane & 15);
      afr[mt] = *(const short8*)(smem + XA_OFF + m * XA_STRIDE + ks * 64 + (lane >> 4) * 16);
    }
#pragma unroll
    for (int ntt = 0; ntt < 4; ++ntt) {
      const int c = ngrp * 64 + ntt * 16 + (lane & 15);
      bfr2[ntt] = *(const short8*)(smem + R2_OFF + c * WBT_STRIDE + ks * 64 + (lane >> 4) * 16);
    }
#pragma unroll
    for (int mt = 0; mt < 4; ++mt)
#pragma unroll
      for (int ntt = 0; ntt < 4; ++ntt)
        acc[mt][ntt] =
            __builtin_amdgcn_mfma_f32_16x16x32_bf16(afr[mt], bfr2[ntt], acc[mt][ntt], 0, 0, 0);
  }
  __syncthreads();  // all xa/wBT reads done; xa region becomes z-tile

  // ---- epilogue: bias + stats + z-tile in LDS ----
  {
    const float* cbl = (const float*)(smem + CB_OFF);
    const float* sal = (const float*)(smem + SA_OFF);
    float* stats = (float*)(smem + ST_OFF);
    float cb0[4], cb1[4], cb2[4];
    int cc[4];
#pragma unroll
    for (int ntt = 0; ntt < 4; ++ntt) {
      cc[ntt] = ngrp * 64 + ntt * 16 + (lane & 15);
      cb0[ntt] = cbl[cc[ntt]];
      cb1[ntt] = cbl[128 + cc[ntt]];
      cb2[ntt] = cbl[256 + cc[ntt]];
    }
    float s1[4] = {0.f, 0.f, 0.f, 0.f}, s2[4] = {0.f, 0.f, 0.f, 0.f};
#pragma unroll
    for (int mt = 0; mt < 4; ++mt)
#pragma unroll
      for (int reg = 0; reg < 4; ++reg) {
        const int m = mgrp * 64 + mt * 16 + (lane >> 4) * 4 + reg;
        const int w = m & 31;
        if (w < 27) {
          const float sa0 = sal[w], sa1 = sal[32 + w], sa2 = sal[64 + w];
#pragma unroll
          for (int ntt = 0; ntt < 4; ++ntt) {
            float val = acc[mt][ntt][reg] + cb0[ntt] * sa0 + cb1[ntt] * sa1 + cb2[ntt] * sa2;
            s1[ntt] += val;
            s2[ntt] += val * val;
            *(unsigned short*)(smem + m * ZL_STRIDE + cc[ntt] * 2) = f2bf(val);
          }
        }
      }
#pragma unroll
    for (int ntt = 0; ntt < 4; ++ntt) {
      float a1 = s1[ntt], a2 = s2[ntt];
      a1 += __shfl_xor(a1, 16); a1 += __shfl_xor(a1, 32);
      a2 += __shfl_xor(a2, 16); a2 += __shfl_xor(a2, 32);
      if ((lane & 48) == 0) {
        atomicAdd(&stats[cc[ntt]], a1);
        atomicAdd(&stats[128 + cc[ntt]], a2);
      }
    }
  }
  __syncthreads();

  // ---- coalesced z store in final layout [n][c][t][w] + partial stats ----
  {
    const int n3 = nt0 >> 9;
    const int t0 = nt0 & 511;  // 8 consecutive nt share n (512 % 8 == 0)
    if (ZBF16) {
      // 128 c * 108 uint-pairs = 13824 uints / 512 thr = 27
#pragma unroll 4
      for (int i = 0; i < 27; ++i) {
        const int idx = i * 512 + tid;
        const int c = idx / 108;
        const int jp = idx % 108;
        const int j0 = jp * 2, j1 = j0 + 1;
        const int tl0 = j0 / 27, w0 = j0 % 27;
        const int tl1 = j1 / 27, w1 = j1 % 27;
        unsigned int b0 = *(unsigned short*)(smem + (tl0 * 32 + w0) * ZL_STRIDE + c * 2);
        unsigned int b1 = *(unsigned short*)(smem + (tl1 * 32 + w1) * ZL_STRIDE + c * 2);
        const size_t base_e = ((size_t)(n3 * 128 + c) * 512 + t0) * 27;
        *(unsigned int*)((char*)zout_bf16 + base_e * 2 + (size_t)jp * 4) = b0 | (b1 << 16);
      }
    } else {
      // 128 c * 216 = 27648 f32 / 512 thr = 54
#pragma unroll 4
      for (int i = 0; i < 54; ++i) {
        const int idx = i * 512 + tid;
        const int c = idx / 216;
        const int j = idx % 216;
        const int tl = j / 27, w = j % 27;
        float v = bf2f(*(unsigned short*)(smem + (tl * 32 + w) * ZL_STRIDE + c * 2));
        zout_f32[((size_t)(n3 * 128 + c) * 512 + (t0 + tl)) * 27 + w] = v;
      }
    }
    if (tid < 256) partial[blk * 256 + tid] = ((float*)(smem + ST_OFF))[tid];
  }
}

// ---------------------------------------------------------------------------
// K2: reduce 2048 per-block partials -> scale[c], shift[c]
// ---------------------------------------------------------------------------
__global__ __launch_bounds__(256) void gcn_k2(const float* __restrict__ partial,
                                              const float* __restrict__ gamma,
                                              const float* __restrict__ beta,
                                              float* __restrict__ ss) {
  __shared__ float lds[256];
  const int tid = threadIdx.x;
  float a0 = 0.f, a1 = 0.f, a2 = 0.f, a3 = 0.f;
  for (int b = 0; b < NBLK; b += 4) {
    a0 += partial[(b + 0) * 256 + tid];
    a1 += partial[(b + 1) * 256 + tid];
    a2 += partial[(b + 2) * 256 + tid];
    a3 += partial[(b + 3) * 256 + tid];
  }
  lds[tid] = (a0 + a1) + (a2 + a3);
  __syncthreads();
  if (tid < 128) {
    const float inv = 1.f / CNT_F;
    float mean = lds[tid] * inv;
    float var = lds[128 + tid] * inv - mean * mean;
    float rstd = rsqrtf(var + 1e-5f);
    float sc = gamma[tid] * rstd;
    ss[tid] = sc;
    ss[128 + tid] = beta[tid] - mean * sc;
  }
}

// ---------------------------------------------------------------------------
// K3: normalize + relu. Block = (n,c): 13824 contiguous elems, c = blk & 127.
// ---------------------------------------------------------------------------
template <bool ZBF16>
__global__ __launch_bounds__(256) void gcn_k3(const unsigned short* __restrict__ zbf,
                                              float* __restrict__ out,
                                              const float* __restrict__ ss) {
  const int blk = blockIdx.x;
  const int tid = threadIdx.x;
  const int c = blk & 127;
  const float sc = ss[c];
  const float sh = ss[128 + c];
  float4* op = (float4*)out + (size_t)blk * 3456;
  if (ZBF16) {
    const ushort4* zp = (const ushort4*)zbf + (size_t)blk * 3456;
#pragma unroll 4
    for (int i = 0; i < 14; ++i) {
      const int idx = i * 256 + tid;
      if (idx < 3456) {
        ushort4 zv = zp[idx];
        float4 o;
        o.x = fmaxf(bf2f(zv.x) * sc + sh, 0.f);
        o.y = fmaxf(bf2f(zv.y) * sc + sh, 0.f);
        o.z = fmaxf(bf2f(zv.z) * sc + sh, 0.f);
        o.w = fmaxf(bf2f(zv.w) * sc + sh, 0.f);
        op[idx] = o;
      }
    }
  } else {
#pragma unroll 4
    for (int i = 0; i < 14; ++i) {
      const int idx = i * 256 + tid;
      if (idx < 3456) {
        float4 zv = op[idx];
        float4 o;
        o.x = fmaxf(zv.x * sc + sh, 0.f);
        o.y = fmaxf(zv.y * sc + sh, 0.f);
        o.z = fmaxf(zv.z * sc + sh, 0.f);
        o.w = fmaxf(zv.w * sc + sh, 0.f);
        op[idx] = o;
      }
    }
  }
}

// ---------------------------------------------------------------------------
extern "C" void kernel_launch(void* const* d_in, const int* in_sizes, int n_in,
                              void* d_out, int out_size, void* d_ws, size_t ws_size,
                              hipStream_t stream) {
  (void)in_sizes; (void)n_in; (void)out_size;
  const float* x = (const float*)d_in[0];
  // d_in[1] = len_x (unused, T fixed at 512)
  const float* cw = (const float*)d_in[2];
  const float* cb = (const float*)d_in[3];
  const float* A = (const float*)d_in[4];
  const float* gm = (const float*)d_in[5];
  const float* bt = (const float*)d_in[6];
  float* out = (float*)d_out;

  const size_t Z_BYTES = (size_t)56623104 * 2;       // z as bf16
  const size_t PART_F = (size_t)NBLK * 256;          // partial floats
  const bool zbf16 = ws_size >= Z_BYTES + PART_F * 4 + 1024;

  if (zbf16) {
    unsigned short* zws = (unsigned short*)d_ws;
    float* partial = (float*)((char*)d_ws + Z_BYTES);
    float* ss = partial + PART_F;
    hipFuncSetAttribute((const void*)gcn_k1<true>,
                        hipFuncAttributeMaxDynamicSharedMemorySize, LDS_BYTES);
    gcn_k1<true><<<NBLK, 512, LDS_BYTES, stream>>>(x, cw, cb, A, nullptr, zws, partial);
    gcn_k2<<<1, 256, 0, stream>>>(partial, gm, bt, ss);
    gcn_k3<true><<<4096, 256, 0, stream>>>(zws, out, ss);
  } else {
    float* partial = (float*)d_ws;
    float* ss = partial + PART_F;
    hipFuncSetAttribute((const void*)gcn_k1<false>,
                        hipFuncAttributeMaxDynamicSharedMemorySize, LDS_BYTES);
    gcn_k1<false><<<NBLK, 512, LDS_BYTES, stream>>>(x, cw, cb, A, out, nullptr, partial);
    gcn_k2<<<1, 256, 0, stream>>>(partial, gm, bt, ss);
    gcn_k3<false><<<4096, 256, 0, stream>>>(nullptr, out, ss);
  }
}

// Round 4
// 537.316 us; speedup vs baseline: 1.0091x; 1.0091x over previous
//
#include <hip/hip_runtime.h>
#include <cstdint>
#include <cstddef>

// x(32,64,512,27) f32, conv_w(384,64), conv_b(384), A(3,27,27), gamma/beta(128)
// out = relu(BN_{n,t,w}(z)) with z[n,c,t,w] = sum_{k,ci,v} cw[k*128+c,ci] x[n,ci,t,v] A[k,v,w]
#define R_NT 4           // (n,t) rows per block
#define NBLK 4096        // 16384 / R_NT
#define CNT_F 442368.0f  // N*T*V per channel

// ---- K1 dynamic LDS layout (bytes) ----
#define XA_STRIDE 400    // xa: 128 rows (m=r*32+w) x 192 bf16 (kci) + pad
#define XS_OFF 51200     // xs: 256 rows (r,ci) x 32 bf16 + pad
#define XS_STRIDE 80
#define ST_OFF 71680     // stats: 256 f32
#define LDS_BYTES 72704  // => 2 blocks/CU
#define ZL_STRIDE 264    // z-tile reuses xa region: 128 rows (c) x 128 bf16 (m) + pad

// ---- ws table offsets (bf16-z path; z at 0) ----
#define Z_BYTES   113246208ull        // 32*128*512*27 * 2
#define WBT_SZ    49152               // 128 c x 192 kci bf16
#define B2_SZ     16384               // 128 c x 32 w f32
#define AOP_SZ    6144                // 3k x 2mt x 64lane x 8 bf16
#define SS_SZ     1024
#define PART2_SZ  65536               // 64 x 256 f32
#define PART_SZ   4194304             // 4096 x 256 f32

typedef __attribute__((ext_vector_type(8))) short short8;
typedef __attribute__((ext_vector_type(4))) float f32x4;

__device__ __forceinline__ unsigned short f2bf(float f) {
  unsigned int u = __float_as_uint(f);
  u = u + 0x7FFFu + ((u >> 16) & 1u);
  return (unsigned short)(u >> 16);
}
__device__ __forceinline__ float bf2f(unsigned short b) {
  return __uint_as_float(((unsigned int)b) << 16);
}

// ---------------------------------------------------------------------------
// K0: precompute wbt (bf16 weights, [c][kci]), bias2[c][w32], aop frag table
// ---------------------------------------------------------------------------
__global__ __launch_bounds__(256) void gcn_k0(const float* __restrict__ cw,
                                              const float* __restrict__ cb,
                                              const float* __restrict__ A,
                                              unsigned short* __restrict__ wbt,
                                              float* __restrict__ bias2,
                                              unsigned short* __restrict__ aopt) {
  const int idx = blockIdx.x * 256 + threadIdx.x;
  if (idx < 12288) {  // wbt u32 pairs: [c][pair p], p = k*32 + ci/2
    const int c = idx / 96, p = idx - c * 96;
    const int k = p >> 5, ci0 = (p & 31) * 2;
    const float* src = cw + ((size_t)(k * 128 + c)) * 64 + ci0;
    ((unsigned int*)wbt)[idx] = (unsigned int)f2bf(src[0]) | ((unsigned int)f2bf(src[1]) << 16);
  } else if (idx < 16384) {  // bias2[c][w32]
    const int e = idx - 12288;
    const int c = e >> 5, w = e & 31;
    float val = 0.f;
    if (w < 27) {
#pragma unroll
      for (int k = 0; k < 3; ++k) {
        float sa = 0.f;
#pragma unroll
        for (int v = 0; v < 27; ++v) sa += A[k * 729 + v * 27 + w];
        val += cb[k * 128 + c] * sa;
      }
    }
    bias2[e] = val;
  } else if (idx < 17920) {  // aop u32 pairs
    const int e2 = (idx - 16384) * 2;  // bf16 flat index
    const int k = e2 >> 10, rem = e2 & 1023;
    const int mt = rem >> 9, rem2 = rem & 511;
    const int ln = rem2 >> 3, j0 = rem2 & 7;
    const int wr = mt * 16 + (ln & 15);
    const int v0 = (ln >> 4) * 8 + j0, v1 = v0 + 1;
    float f0 = (wr < 27 && v0 < 27) ? A[k * 729 + v0 * 27 + wr] : 0.f;
    float f1 = (wr < 27 && v1 < 27) ? A[k * 729 + v1 * 27 + wr] : 0.f;
    ((unsigned int*)aopt)[idx - 16384] = (unsigned int)f2bf(f0) | ((unsigned int)f2bf(f1) << 16);
  }
}

// ---------------------------------------------------------------------------
// K1: 4 (n,t) rows per block. phase A: xa = x*A (MFMA). phase B: z = xa*w (MFMA).
// ---------------------------------------------------------------------------
template <bool ZBF16>
__global__ __launch_bounds__(512, 4) void gcn_k1(
    const float* __restrict__ x, const unsigned short* __restrict__ wbt,
    const float* __restrict__ bias2, const unsigned short* __restrict__ aopt,
    float* __restrict__ zout_f32, unsigned short* __restrict__ zout_bf16,
    float* __restrict__ partial) {
  extern __shared__ char smem[];
  const int tid = threadIdx.x;
  const int lane = tid & 63;
  const int wid = tid >> 6;
  const int blk = blockIdx.x;
  const int nt0 = blk * R_NT;
  const int n = nt0 >> 9;
  const int t0 = nt0 & 511;  // multiple of 4; all 4 rows share n

  // aop fragment table loads (coalesced b128)
  short8 aop[3][2];
#pragma unroll
  for (int k = 0; k < 3; ++k)
#pragma unroll
    for (int mt = 0; mt < 2; ++mt)
      aop[k][mt] = *(const short8*)(aopt + ((k * 2 + mt) * 64 + lane) * 8);

  // ---- x -> xs (bf16). thread pair per row: h=0 -> v0..13, h=1 -> v14..26 ----
  {
    const int idx = tid >> 1, h = tid & 1;
    const int r = idx >> 6, ci = idx & 63;
    const float* xr = x + ((size_t)(n * 64 + ci) * 512 + t0 + r) * 27;
    unsigned int* row = (unsigned int*)(smem + XS_OFF + (r * 64 + ci) * XS_STRIDE);
    if (h == 0) {
      float f[14];
#pragma unroll
      for (int v = 0; v < 14; ++v) f[v] = xr[v];
#pragma unroll
      for (int p = 0; p < 7; ++p)
        row[p] = (unsigned int)f2bf(f[2 * p]) | ((unsigned int)f2bf(f[2 * p + 1]) << 16);
    } else {
      float f[13];
#pragma unroll
      for (int v = 0; v < 13; ++v) f[v] = xr[14 + v];
#pragma unroll
      for (int p = 7; p < 16; ++p) {
        const int v0 = 2 * p - 14, v1 = v0 + 1;
        unsigned int b0 = (v0 < 13) ? (unsigned int)f2bf(f[v0]) : 0u;
        unsigned int b1 = (v1 < 13) ? (unsigned int)f2bf(f[v1]) : 0u;
        row[p] = b0 | (b1 << 16);
      }
    }
  }
  if (tid < 256) ((float*)(smem + ST_OFF))[tid] = 0.f;
  __syncthreads();

  // ---- phase A: wave (r2 = wid>>1, half = wid&1); writes xa[m][kci] ----
  {
    const int r2 = wid >> 1, half = wid & 1;
    short8 bfr[2];
#pragma unroll
    for (int nt2 = 0; nt2 < 2; ++nt2) {
      const int ci2 = half * 32 + nt2 * 16 + (lane & 15);
      bfr[nt2] = *(const short8*)(smem + XS_OFF + (r2 * 64 + ci2) * XS_STRIDE + (lane >> 4) * 16);
    }
#pragma unroll
    for (int k = 0; k < 3; ++k)
#pragma unroll
      for (int mt = 0; mt < 2; ++mt)
#pragma unroll
        for (int nt2 = 0; nt2 < 2; ++nt2) {
          f32x4 d = {0.f, 0.f, 0.f, 0.f};
          d = __builtin_amdgcn_mfma_f32_16x16x32_bf16(aop[k][mt], bfr[nt2], d, 0, 0, 0);
          const int ciW = half * 32 + nt2 * 16 + (lane & 15);
          const int wb = mt * 16 + (lane >> 4) * 4;
#pragma unroll
          for (int reg = 0; reg < 4; ++reg) {
            const int m = r2 * 32 + wb + reg;  // pad rows (w>=27) get exact 0
            *(unsigned short*)(smem + m * XA_STRIDE + (k * 64 + ciW) * 2) = f2bf(d[reg]);
          }
        }
  }
  __syncthreads();

  // ---- phase B: M=128 (m), N=128 (c), K=192. wave tile 32x64. B from global. ----
  // K-step = one 16x16x32 MFMA = 32 bf16 = 64 BYTES per step.
  const int mgrp = wid >> 1;
  const int ngrp = wid & 1;
  f32x4 acc[2][4];
#pragma unroll
  for (int a = 0; a < 2; ++a)
#pragma unroll
    for (int b = 0; b < 4; ++b) acc[a][b] = (f32x4){0.f, 0.f, 0.f, 0.f};

#pragma unroll 2
  for (int ks = 0; ks < 6; ++ks) {
    short8 afr[2], bfrg[4];
#pragma unroll
    for (int mt = 0; mt < 2; ++mt) {
      const int m = mgrp * 32 + mt * 16 + (lane & 15);
      afr[mt] = *(const short8*)(smem + m * XA_STRIDE + ks * 64 + (lane >> 4) * 16);
    }
#pragma unroll
    for (int ntt = 0; ntt < 4; ++ntt) {
      const int c = ngrp * 64 + ntt * 16 + (lane & 15);
      bfrg[ntt] = *(const short8*)(wbt + c * 192 + ks * 32 + (lane >> 4) * 8);
    }
#pragma unroll
    for (int mt = 0; mt < 2; ++mt)
#pragma unroll
      for (int ntt = 0; ntt < 4; ++ntt)
        acc[mt][ntt] =
            __builtin_amdgcn_mfma_f32_16x16x32_bf16(afr[mt], bfrg[ntt], acc[mt][ntt], 0, 0, 0);
  }
  __syncthreads();  // xa reads done; region becomes z-tile [c][m]

  // ---- epilogue: bias + stats + packed z-tile writes ----
  {
    float* stats = (float*)(smem + ST_OFF);
    int cc[4];
#pragma unroll
    for (int ntt = 0; ntt < 4; ++ntt) cc[ntt] = ngrp * 64 + ntt * 16 + (lane & 15);
    float s1[4] = {0.f, 0.f, 0.f, 0.f}, s2[4] = {0.f, 0.f, 0.f, 0.f};
#pragma unroll
    for (int mt = 0; mt < 2; ++mt) {
      const int mb = mgrp * 32 + mt * 16 + (lane >> 4) * 4;
      unsigned int pk[4][2];
#pragma unroll
      for (int ntt = 0; ntt < 4; ++ntt) { pk[ntt][0] = 0u; pk[ntt][1] = 0u; }
#pragma unroll
      for (int reg = 0; reg < 4; ++reg) {
        const int w = (mb + reg) & 31;
        if (w < 27) {
#pragma unroll
          for (int ntt = 0; ntt < 4; ++ntt) {
            float val = acc[mt][ntt][reg] + bias2[cc[ntt] * 32 + w];
            s1[ntt] += val;
            s2[ntt] += val * val;
            pk[ntt][reg >> 1] |= ((unsigned int)f2bf(val)) << ((reg & 1) * 16);
          }
        }
      }
#pragma unroll
      for (int ntt = 0; ntt < 4; ++ntt)
        *(uint2*)(smem + cc[ntt] * ZL_STRIDE + mb * 2) = make_uint2(pk[ntt][0], pk[ntt][1]);
    }
#pragma unroll
    for (int ntt = 0; ntt < 4; ++ntt) {
      float a1 = s1[ntt], a2 = s2[ntt];
      a1 += __shfl_xor(a1, 16); a1 += __shfl_xor(a1, 32);
      a2 += __shfl_xor(a2, 16); a2 += __shfl_xor(a2, 32);
      if ((lane & 48) == 0) {
        atomicAdd(&stats[cc[ntt]], a1);
        atomicAdd(&stats[128 + cc[ntt]], a2);
      }
    }
  }
  __syncthreads();

  // ---- coalesced global z store in [n][c][t][w] + partial stats ----
  if (ZBF16) {
    // 128 c x 54 u32 = 6912
#pragma unroll
    for (int i = 0; i < 14; ++i) {
      const int idx = i * 512 + tid;
      if (idx < 6912) {
        const int c = idx / 54;
        const int d = idx - c * 54;
        const int j0 = 2 * d, j1 = j0 + 1;
        const int tl0 = j0 / 27, w0 = j0 - 27 * tl0;
        const int tl1 = j1 / 27, w1 = j1 - 27 * tl1;
        unsigned int b0 = *(unsigned short*)(smem + c * ZL_STRIDE + (tl0 * 32 + w0) * 2);
        unsigned int b1 = *(unsigned short*)(smem + c * ZL_STRIDE + (tl1 * 32 + w1) * 2);
        const size_t base = ((size_t)(n * 128 + c) * 512 + t0) * 27;  // *2 bytes => 4-aligned
        *(unsigned int*)((char*)zout_bf16 + base * 2 + (size_t)j0 * 2) = b0 | (b1 << 16);
      }
    }
  } else {
    // 128 c x 108 f32 = 13824
#pragma unroll
    for (int i = 0; i < 27; ++i) {
      const int idx = i * 512 + tid;
      const int c = idx / 108;
      const int d = idx - c * 108;
      const int tl = d / 27, w = d - 27 * tl;
      float v = bf2f(*(unsigned short*)(smem + c * ZL_STRIDE + (tl * 32 + w) * 2));
      zout_f32[((size_t)(n * 128 + c) * 512 + (t0 + tl)) * 27 + w] = v;
    }
  }
  if (tid < 256) partial[(size_t)blk * 256 + tid] = ((float*)(smem + ST_OFF))[tid];
}

// ---------------------------------------------------------------------------
// K2a: 64 blocks each sum 64 rows of partial[4096][256] -> part2[64][256]
// ---------------------------------------------------------------------------
__global__ __launch_bounds__(256) void gcn_k2a(const float* __restrict__ partial,
                                               float* __restrict__ part2) {
  const int b = blockIdx.x;
  const int tid = threadIdx.x;
  const float* p = partial + (size_t)b * 64 * 256 + tid;
  float s0 = 0.f, s1 = 0.f, s2 = 0.f, s3 = 0.f;
#pragma unroll 4
  for (int r = 0; r < 64; r += 4) {
    s0 += p[(r + 0) * 256];
    s1 += p[(r + 1) * 256];
    s2 += p[(r + 2) * 256];
    s3 += p[(r + 3) * 256];
  }
  part2[b * 256 + tid] = (s0 + s1) + (s2 + s3);
}

// K2b: final reduce + scale/shift
__global__ __launch_bounds__(256) void gcn_k2b(const float* __restrict__ part2,
                                               const float* __restrict__ gamma,
                                               const float* __restrict__ beta,
                                               float* __restrict__ ss) {
  __shared__ float lds[256];
  const int tid = threadIdx.x;
  float s = 0.f;
#pragma unroll 4
  for (int r = 0; r < 64; ++r) s += part2[r * 256 + tid];
  lds[tid] = s;
  __syncthreads();
  if (tid < 128) {
    const float inv = 1.f / CNT_F;
    float mean = lds[tid] * inv;
    float var = lds[128 + tid] * inv - mean * mean;
    float rstd = rsqrtf(var + 1e-5f);
    float sc = gamma[tid] * rstd;
    ss[tid] = sc;
    ss[128 + tid] = beta[tid] - mean * sc;
  }
}

// ---------------------------------------------------------------------------
// K3: normalize + relu. Block = (n,c): 13824 contiguous elems.
// ---------------------------------------------------------------------------
template <bool ZBF16>
__global__ __launch_bounds__(256) void gcn_k3(const unsigned short* __restrict__ zbf,
                                              float* __restrict__ out,
                                              const float* __restrict__ ss) {
  const int blk = blockIdx.x;
  const int tid = threadIdx.x;
  const int c = blk & 127;
  const float sc = ss[c];
  const float sh = ss[128 + c];
  float4* op = (float4*)out + (size_t)blk * 3456;
  if (ZBF16) {
    const ushort4* zp = (const ushort4*)zbf + (size_t)blk * 3456;
#pragma unroll 4
    for (int i = 0; i < 14; ++i) {
      const int idx = i * 256 + tid;
      if (idx < 3456) {
        ushort4 zv = zp[idx];
        float4 o;
        o.x = fmaxf(bf2f(zv.x) * sc + sh, 0.f);
        o.y = fmaxf(bf2f(zv.y) * sc + sh, 0.f);
        o.z = fmaxf(bf2f(zv.z) * sc + sh, 0.f);
        o.w = fmaxf(bf2f(zv.w) * sc + sh, 0.f);
        op[idx] = o;
      }
    }
  } else {
#pragma unroll 4
    for (int i = 0; i < 14; ++i) {
      const int idx = i * 256 + tid;
      if (idx < 3456) {
        float4 zv = op[idx];
        float4 o;
        o.x = fmaxf(zv.x * sc + sh, 0.f);
        o.y = fmaxf(zv.y * sc + sh, 0.f);
        o.z = fmaxf(zv.z * sc + sh, 0.f);
        o.w = fmaxf(zv.w * sc + sh, 0.f);
        op[idx] = o;
      }
    }
  }
}

// ---------------------------------------------------------------------------
extern "C" void kernel_launch(void* const* d_in, const int* in_sizes, int n_in,
                              void* d_out, int out_size, void* d_ws, size_t ws_size,
                              hipStream_t stream) {
  (void)in_sizes; (void)n_in; (void)out_size;
  const float* x = (const float*)d_in[0];
  const float* cw = (const float*)d_in[2];
  const float* cb = (const float*)d_in[3];
  const float* A = (const float*)d_in[4];
  const float* gm = (const float*)d_in[5];
  const float* bt = (const float*)d_in[6];
  float* out = (float*)d_out;

  const size_t need_bf16 = Z_BYTES + WBT_SZ + B2_SZ + AOP_SZ + SS_SZ + PART2_SZ + PART_SZ;
  const bool zbf16 = ws_size >= need_bf16;
  const size_t zoff = zbf16 ? Z_BYTES : 0;

  char* base = (char*)d_ws;
  unsigned short* wbt = (unsigned short*)(base + zoff);
  float* bias2 = (float*)(base + zoff + WBT_SZ);
  unsigned short* aopt = (unsigned short*)(base + zoff + WBT_SZ + B2_SZ);
  float* ssv = (float*)(base + zoff + WBT_SZ + B2_SZ + AOP_SZ);
  float* part2 = (float*)(base + zoff + WBT_SZ + B2_SZ + AOP_SZ + SS_SZ);
  float* partial = (float*)(base + zoff + WBT_SZ + B2_SZ + AOP_SZ + SS_SZ + PART2_SZ);

  gcn_k0<<<70, 256, 0, stream>>>(cw, cb, A, wbt, bias2, aopt);

  if (zbf16) {
    unsigned short* zws = (unsigned short*)d_ws;
    hipFuncSetAttribute((const void*)gcn_k1<true>,
                        hipFuncAttributeMaxDynamicSharedMemorySize, LDS_BYTES);
    gcn_k1<true><<<NBLK, 512, LDS_BYTES, stream>>>(x, wbt, bias2, aopt, nullptr, zws, partial);
    gcn_k2a<<<64, 256, 0, stream>>>(partial, part2);
    gcn_k2b<<<1, 256, 0, stream>>>(part2, gm, bt, ssv);
    gcn_k3<true><<<4096, 256, 0, stream>>>(zws, out, ssv);
  } else {
    hipFuncSetAttribute((const void*)gcn_k1<false>,
                        hipFuncAttributeMaxDynamicSharedMemorySize, LDS_BYTES);
    gcn_k1<false><<<NBLK, 512, LDS_BYTES, stream>>>(x, wbt, bias2, aopt, out, nullptr, partial);
    gcn_k2a<<<64, 256, 0, stream>>>(partial, part2);
    gcn_k2b<<<1, 256, 0, stream>>>(part2, gm, bt, ssv);
    gcn_k3<false><<<4096, 256, 0, stream>>>(nullptr, out, ssv);
  }
}